// Round 1
// baseline (2942.136 us; speedup 1.0000x reference)
//
#include <hip/hip_runtime.h>

#define D 128

// ---------------- small prep kernels ----------------

__global__ __launch_bounds__(256) void k_transpose_w(const float* __restrict__ W,
                                                     float* __restrict__ Wt) {
  int t = blockIdx.x * 256 + threadIdx.x;   // 16384 threads
  int o = t >> 7;
  int k = t & 127;
  Wt[k * D + o] = W[o * D + k];
}

__global__ __launch_bounds__(256) void k_degree(const int* __restrict__ ei,
                                                int* __restrict__ deg, int E) {
  int e = blockIdx.x * 256 + threadIdx.x;
  if (e < E) {
    atomicAdd(&deg[ei[e]], 1);       // row endpoint
    atomicAdd(&deg[ei[E + e]], 1);   // col endpoint
  }
}

__global__ __launch_bounds__(256) void k_dis(const int* __restrict__ deg,
                                             float* __restrict__ dis, int n) {
  int i = blockIdx.x * 256 + threadIdx.x;
  if (i < n) dis[i] = rsqrtf((float)(deg[i] + 1));  // +1 = self loop; always > 0
}

// ---------------- fused GEMM: g = dis * (x @ W^T + b); out seeded with g ----------------
// Block: 256 threads = (co 0..31 col-float4, rq 0..7 row-quad). 128 rows/block,
// processed in 4 batches of 32 rows. W^T (64 KB) + x-transposed tile (16 KB) in LDS
// -> 80 KB -> 2 blocks/CU. 16 FMA per ds_read_b128 of W -> VALU-bound.
__global__ __launch_bounds__(256) void k_gemm(
    const float* __restrict__ x, const float* __restrict__ Wt,
    const float* __restrict__ bias, const float* __restrict__ dis,
    float* __restrict__ g, float* __restrict__ out, int n) {
  __shared__ float swt[D * D];   // [k][o], 64 KB
  __shared__ float sxt[D][32];   // [k][r], 16 KB

  for (int i = threadIdx.x; i < D * D; i += 256) swt[i] = Wt[i];

  const int co = threadIdx.x & 31;   // column float4 group
  const int rq = threadIdx.x >> 5;   // row quad 0..7
  const float4 b4 = ((const float4*)bias)[co];
  const int row0 = blockIdx.x * 128;

  for (int batch = 0; batch < 4; ++batch) {
    const int base = row0 + batch * 32;
    __syncthreads();   // protect sxt reuse (also covers swt before first use)
    // stage 32 rows of x, transposed: sxt[k][r] = x[base+r][k]
    for (int j = 0; j < 4; ++j) {
      int idx = threadIdx.x + j * 256;
      int r = idx >> 5;
      int kg = idx & 31;
      int grow = base + r;
      float4 v = make_float4(0.f, 0.f, 0.f, 0.f);
      if (grow < n) v = ((const float4*)x)[(size_t)grow * 32 + kg];
      sxt[4 * kg + 0][r] = v.x;
      sxt[4 * kg + 1][r] = v.y;
      sxt[4 * kg + 2][r] = v.z;
      sxt[4 * kg + 3][r] = v.w;
    }
    __syncthreads();

    float4 a0 = b4, a1 = b4, a2 = b4, a3 = b4;
#pragma unroll 8
    for (int k = 0; k < D; ++k) {
      const float4 w4 = *(const float4*)(swt + k * D + 4 * co);
      const float4 x4 = *(const float4*)(&sxt[k][4 * rq]);
      a0.x = fmaf(x4.x, w4.x, a0.x); a0.y = fmaf(x4.x, w4.y, a0.y);
      a0.z = fmaf(x4.x, w4.z, a0.z); a0.w = fmaf(x4.x, w4.w, a0.w);
      a1.x = fmaf(x4.y, w4.x, a1.x); a1.y = fmaf(x4.y, w4.y, a1.y);
      a1.z = fmaf(x4.y, w4.z, a1.z); a1.w = fmaf(x4.y, w4.w, a1.w);
      a2.x = fmaf(x4.z, w4.x, a2.x); a2.y = fmaf(x4.z, w4.y, a2.y);
      a2.z = fmaf(x4.z, w4.z, a2.z); a2.w = fmaf(x4.z, w4.w, a2.w);
      a3.x = fmaf(x4.w, w4.x, a3.x); a3.y = fmaf(x4.w, w4.y, a3.y);
      a3.z = fmaf(x4.w, w4.z, a3.z); a3.w = fmaf(x4.w, w4.w, a3.w);
    }

    const int r = base + rq * 4;
    float4 accs[4] = {a0, a1, a2, a3};
#pragma unroll
    for (int j = 0; j < 4; ++j) {
      int rr = r + j;
      if (rr < n) {
        float s = dis[rr];
        float4 a = accs[j];
        a.x *= s; a.y *= s; a.z *= s; a.w *= s;
        ((float4*)g)[(size_t)rr * 32 + co] = a;
        ((float4*)out)[(size_t)rr * 32 + co] = a;  // self-loop seed
      }
    }
  }
}

// ---------------- edge scatter: out[col] += g[row], out[row] += g[col] ----------------
// 32 threads per edge, one float4 lane each. ~205M f32 atomics total.
__global__ __launch_bounds__(256) void k_scatter(const int* __restrict__ ei,
                                                 const float* __restrict__ g,
                                                 float* __restrict__ out, int E) {
  int t = blockIdx.x * 256 + threadIdx.x;
  int e = t >> 5;
  int d = (t & 31) << 2;
  if (e < E) {
    int r = ei[e];
    int c = ei[E + e];
    const float4 gr = *(const float4*)(g + (size_t)r * D + d);
    const float4 gc = *(const float4*)(g + (size_t)c * D + d);
    float* oc = out + (size_t)c * D + d;
    float* orr = out + (size_t)r * D + d;
    unsafeAtomicAdd(oc + 0, gr.x); unsafeAtomicAdd(oc + 1, gr.y);
    unsafeAtomicAdd(oc + 2, gr.z); unsafeAtomicAdd(oc + 3, gr.w);
    unsafeAtomicAdd(orr + 0, gc.x); unsafeAtomicAdd(orr + 1, gc.y);
    unsafeAtomicAdd(orr + 2, gc.z); unsafeAtomicAdd(orr + 3, gc.w);
  }
}

// ---------------- finalize: out = relu(dis * out) ----------------
__global__ __launch_bounds__(256) void k_final(float* __restrict__ out,
                                               const float* __restrict__ dis, int n4) {
  int t = blockIdx.x * 256 + threadIdx.x;  // over n*32 float4s
  if (t < n4) {
    int i = t >> 5;
    float s = dis[i];
    float4 v = ((float4*)out)[t];
    v.x = fmaxf(v.x * s, 0.f);
    v.y = fmaxf(v.y * s, 0.f);
    v.z = fmaxf(v.z * s, 0.f);
    v.w = fmaxf(v.w * s, 0.f);
    ((float4*)out)[t] = v;
  }
}

extern "C" void kernel_launch(void* const* d_in, const int* in_sizes, int n_in,
                              void* d_out, int out_size, void* d_ws, size_t ws_size,
                              hipStream_t stream) {
  const float* x  = (const float*)d_in[0];
  const int*   ei = (const int*)d_in[1];
  const float* W  = (const float*)d_in[2];
  const float* b  = (const float*)d_in[3];
  float* out = (float*)d_out;

  const int N = in_sizes[0] / D;
  const int E = in_sizes[1] / 2;

  char* ws = (char*)d_ws;
  size_t off = 0;
  float* Wt = (float*)(ws + off); off += (size_t)D * D * 4;            // 64 KB
  int* deg  = (int*)(ws + off);   off += (size_t)N * 4;
  off = (off + 255) & ~(size_t)255;
  float* dis = (float*)(ws + off); off += (size_t)N * 4;
  off = (off + 255) & ~(size_t)255;
  float* g   = (float*)(ws + off);                                      // N*128 f32, 51.2 MB

  hipMemsetAsync(deg, 0, (size_t)N * 4, stream);
  k_transpose_w<<<(D * D + 255) / 256, 256, 0, stream>>>(W, Wt);
  k_degree<<<(E + 255) / 256, 256, 0, stream>>>(ei, deg, E);
  k_dis<<<(N + 255) / 256, 256, 0, stream>>>(deg, dis, N);
  k_gemm<<<(N + 127) / 128, 256, 0, stream>>>(x, Wt, b, dis, g, out, N);
  k_scatter<<<(int)(((size_t)E * 32 + 255) / 256), 256, 0, stream>>>(ei, g, out, E);
  k_final<<<(N * 32 + 255) / 256, 256, 0, stream>>>(out, dis, N * 32);
}

// Round 2
// 513.116 us; speedup vs baseline: 5.7339x; 5.7339x over previous
//
#include <hip/hip_runtime.h>

#define D 128

// ---------------- small prep kernels ----------------

__global__ __launch_bounds__(256) void k_transpose_w(const float* __restrict__ W,
                                                     float* __restrict__ Wt) {
  int t = blockIdx.x * 256 + threadIdx.x;   // 16384 threads
  int o = t >> 7;
  int k = t & 127;
  Wt[k * D + o] = W[o * D + k];
}

__global__ __launch_bounds__(256) void k_degree(const int* __restrict__ ei,
                                                int* __restrict__ deg, int E) {
  int e = blockIdx.x * 256 + threadIdx.x;
  if (e < E) {
    atomicAdd(&deg[ei[e]], 1);       // row endpoint
    atomicAdd(&deg[ei[E + e]], 1);   // col endpoint
  }
}

__global__ __launch_bounds__(256) void k_dis(const int* __restrict__ deg,
                                             float* __restrict__ dis, int n) {
  int i = blockIdx.x * 256 + threadIdx.x;
  if (i < n) dis[i] = rsqrtf((float)(deg[i] + 1));  // +1 = self loop; always > 0
}

// ---------------- CSR build: blocksum -> scan blocksums -> per-block scan ----------------

__global__ __launch_bounds__(256) void k_blocksum(const int* __restrict__ deg,
                                                  int* __restrict__ bsum, int n) {
  __shared__ int s[256];
  int i = blockIdx.x * 256 + threadIdx.x;
  s[threadIdx.x] = (i < n) ? deg[i] : 0;
  __syncthreads();
  for (int o = 128; o > 0; o >>= 1) {
    if (threadIdx.x < o) s[threadIdx.x] += s[threadIdx.x + o];
    __syncthreads();
  }
  if (threadIdx.x == 0) bsum[blockIdx.x] = s[0];
}

// single block, exclusive-scans bsum[nb] in place (nb <= 512)
__global__ __launch_bounds__(512) void k_scanbsum(int* __restrict__ bsum, int nb) {
  __shared__ int s[512];
  int v = (threadIdx.x < nb) ? bsum[threadIdx.x] : 0;
  s[threadIdx.x] = v;
  __syncthreads();
  for (int o = 1; o < 512; o <<= 1) {
    int t = (threadIdx.x >= (unsigned)o) ? s[threadIdx.x - o] : 0;
    __syncthreads();
    s[threadIdx.x] += t;
    __syncthreads();
  }
  if (threadIdx.x < nb) bsum[threadIdx.x] = s[threadIdx.x] - v;  // exclusive
}

__global__ __launch_bounds__(256) void k_scandeg(const int* __restrict__ deg,
                                                 const int* __restrict__ bofs,
                                                 int* __restrict__ offsets,
                                                 int* __restrict__ cursor, int n) {
  __shared__ int s[256];
  int i = blockIdx.x * 256 + threadIdx.x;
  int v = (i < n) ? deg[i] : 0;
  s[threadIdx.x] = v;
  __syncthreads();
  for (int o = 1; o < 256; o <<= 1) {
    int t = (threadIdx.x >= (unsigned)o) ? s[threadIdx.x - o] : 0;
    __syncthreads();
    s[threadIdx.x] += t;
    __syncthreads();
  }
  if (i < n) {
    int incl = s[threadIdx.x] + bofs[blockIdx.x];
    offsets[i + 1] = incl;           // offsets[i+1] = sum deg[0..i]
    cursor[i] = incl - v;            // exclusive
    if (i == 0) offsets[0] = 0;
  }
}

__global__ __launch_bounds__(256) void k_fill(const int* __restrict__ ei,
                                              int* __restrict__ cursor,
                                              int* __restrict__ adj, int E) {
  int e = blockIdx.x * 256 + threadIdx.x;
  if (e < E) {
    int r = ei[e];
    int c = ei[E + e];
    int p = atomicAdd(&cursor[r], 1); adj[p] = c;
    int q = atomicAdd(&cursor[c], 1); adj[q] = r;
  }
}

// ---------------- fused GEMM: g = dis * (x @ W^T + b) ----------------
__global__ __launch_bounds__(256) void k_gemm(
    const float* __restrict__ x, const float* __restrict__ Wt,
    const float* __restrict__ bias, const float* __restrict__ dis,
    float* __restrict__ g, int n) {
  __shared__ float swt[D * D];   // [k][o], 64 KB
  __shared__ float sxt[D][32];   // [k][r], 16 KB

  for (int i = threadIdx.x; i < D * D; i += 256) swt[i] = Wt[i];

  const int co = threadIdx.x & 31;   // column float4 group
  const int rq = threadIdx.x >> 5;   // row quad 0..7
  const float4 b4 = ((const float4*)bias)[co];
  const int row0 = blockIdx.x * 128;

  for (int batch = 0; batch < 4; ++batch) {
    const int base = row0 + batch * 32;
    __syncthreads();
    for (int j = 0; j < 4; ++j) {
      int idx = threadIdx.x + j * 256;
      int r = idx >> 5;
      int kg = idx & 31;
      int grow = base + r;
      float4 v = make_float4(0.f, 0.f, 0.f, 0.f);
      if (grow < n) v = ((const float4*)x)[(size_t)grow * 32 + kg];
      sxt[4 * kg + 0][r] = v.x;
      sxt[4 * kg + 1][r] = v.y;
      sxt[4 * kg + 2][r] = v.z;
      sxt[4 * kg + 3][r] = v.w;
    }
    __syncthreads();

    float4 a0 = b4, a1 = b4, a2 = b4, a3 = b4;
#pragma unroll 8
    for (int k = 0; k < D; ++k) {
      const float4 w4 = *(const float4*)(swt + k * D + 4 * co);
      const float4 x4 = *(const float4*)(&sxt[k][4 * rq]);
      a0.x = fmaf(x4.x, w4.x, a0.x); a0.y = fmaf(x4.x, w4.y, a0.y);
      a0.z = fmaf(x4.x, w4.z, a0.z); a0.w = fmaf(x4.x, w4.w, a0.w);
      a1.x = fmaf(x4.y, w4.x, a1.x); a1.y = fmaf(x4.y, w4.y, a1.y);
      a1.z = fmaf(x4.y, w4.z, a1.z); a1.w = fmaf(x4.y, w4.w, a1.w);
      a2.x = fmaf(x4.z, w4.x, a2.x); a2.y = fmaf(x4.z, w4.y, a2.y);
      a2.z = fmaf(x4.z, w4.z, a2.z); a2.w = fmaf(x4.z, w4.w, a2.w);
      a3.x = fmaf(x4.w, w4.x, a3.x); a3.y = fmaf(x4.w, w4.y, a3.y);
      a3.z = fmaf(x4.w, w4.z, a3.z); a3.w = fmaf(x4.w, w4.w, a3.w);
    }

    const int r = base + rq * 4;
    float4 accs[4] = {a0, a1, a2, a3};
#pragma unroll
    for (int j = 0; j < 4; ++j) {
      int rr = r + j;
      if (rr < n) {
        float s = dis[rr];
        float4 a = accs[j];
        a.x *= s; a.y *= s; a.z *= s; a.w *= s;
        ((float4*)g)[(size_t)rr * 32 + co] = a;
      }
    }
  }
}

// ---------------- pull aggregation: out[v] = relu(dis[v]*(g[v] + sum_{u in adj(v)} g[u]))
// one wave per node; lane owns 2 floats of the 128-dim row.
__global__ __launch_bounds__(256) void k_aggregate(const int* __restrict__ offsets,
                                                   const int* __restrict__ adj,
                                                   const float* __restrict__ g,
                                                   const float* __restrict__ dis,
                                                   float* __restrict__ out, int n) {
  int w = blockIdx.x * 4 + (threadIdx.x >> 6);
  if (w >= n) return;
  int lane = threadIdx.x & 63;
  const float2* g2 = (const float2*)g;

  float2 acc = g2[(size_t)w * 64 + lane];   // self-loop term
  int s = offsets[w];
  int e = offsets[w + 1];
  for (int base = s; base < e; base += 64) {
    int cnt = e - base; if (cnt > 64) cnt = 64;
    int my = (base + lane < e) ? adj[base + lane] : 0;
    for (int k = 0; k < cnt; ++k) {
      int u = __shfl(my, k);
      float2 v = g2[(size_t)u * 64 + lane];
      acc.x += v.x;
      acc.y += v.y;
    }
  }
  float sc = dis[w];
  float2 o;
  o.x = fmaxf(acc.x * sc, 0.f);
  o.y = fmaxf(acc.y * sc, 0.f);
  ((float2*)out)[(size_t)w * 64 + lane] = o;
}

extern "C" void kernel_launch(void* const* d_in, const int* in_sizes, int n_in,
                              void* d_out, int out_size, void* d_ws, size_t ws_size,
                              hipStream_t stream) {
  const float* x  = (const float*)d_in[0];
  const int*   ei = (const int*)d_in[1];
  const float* W  = (const float*)d_in[2];
  const float* b  = (const float*)d_in[3];
  float* out = (float*)d_out;

  const int N = in_sizes[0] / D;
  const int E = in_sizes[1] / 2;
  const int nb = (N + 255) / 256;          // scan blocks (391 <= 512)

  char* ws = (char*)d_ws;
  size_t off = 0;
  float* Wt   = (float*)(ws + off); off += (size_t)D * D * 4;     // 64 KB
  int* deg    = (int*)(ws + off);   off += (size_t)N * 4;
  off = (off + 255) & ~(size_t)255;
  float* dis  = (float*)(ws + off); off += (size_t)N * 4;
  off = (off + 255) & ~(size_t)255;
  int* bsum   = (int*)(ws + off);   off += (size_t)512 * 4;
  int* offs   = (int*)(ws + off);   off += (size_t)(N + 1) * 4;
  off = (off + 255) & ~(size_t)255;
  int* cursor = (int*)(ws + off);   off += (size_t)N * 4;
  off = (off + 255) & ~(size_t)255;
  int* adj    = (int*)(ws + off);   off += (size_t)2 * E * 4;     // 6.4 MB
  off = (off + 255) & ~(size_t)255;
  float* g    = (float*)(ws + off);                               // 51.2 MB

  hipMemsetAsync(deg, 0, (size_t)N * 4, stream);
  k_transpose_w<<<(D * D + 255) / 256, 256, 0, stream>>>(W, Wt);
  k_degree<<<(E + 255) / 256, 256, 0, stream>>>(ei, deg, E);
  k_dis<<<(N + 255) / 256, 256, 0, stream>>>(deg, dis, N);
  k_blocksum<<<nb, 256, 0, stream>>>(deg, bsum, N);
  k_scanbsum<<<1, 512, 0, stream>>>(bsum, nb);
  k_scandeg<<<nb, 256, 0, stream>>>(deg, bsum, offs, cursor, N);
  k_fill<<<(E + 255) / 256, 256, 0, stream>>>(ei, cursor, adj, E);
  k_gemm<<<(N + 127) / 128, 256, 0, stream>>>(x, Wt, b, dis, g, N);
  k_aggregate<<<(N + 3) / 4, 256, 0, stream>>>(offs, adj, g, dis, out, N);
}